// Round 4
// baseline (1085.628 us; speedup 1.0000x reference)
//
#include <hip/hip_runtime.h>
#include <math.h>

#define N_NODES 20000
#define N_EDGES 320000
#define HH      256
#define GG      128
#define FN      64
#define FE      16

// fast device math: tanh/sigmoid via v_exp_f32
__device__ __forceinline__ float fast_sigmoid(float x) {
    return 1.f / (1.f + __expf(-x));
}
__device__ __forceinline__ float fast_tanh(float x) {
    // 1 - 2/(e^{2x}+1); exact saturation at +/-inf
    return 1.f - 2.f / (__expf(2.f * x) + 1.f);
}

// ---------------------------------------------------------------------------
// CSR build: histogram / two-level scan / permuting scatter
// ---------------------------------------------------------------------------
__global__ void hist_k(const int* __restrict__ dst, int* __restrict__ cnt) {
    int e = blockIdx.x * blockDim.x + threadIdx.x;
    if (e < N_EDGES) atomicAdd(&cnt[dst[e]], 1);
}

// per-256-block exclusive scan; block sums out
__global__ __launch_bounds__(256) void scan1_k(const int* __restrict__ cnt,
                                               int* __restrict__ ex,
                                               int* __restrict__ bsum) {
    int b = blockIdx.x, t = threadIdx.x;
    int i = b * 256 + t;
    int v = (i < N_NODES) ? cnt[i] : 0;
    int lane = t & 63, w = t >> 6;
    int incl = v;
#pragma unroll
    for (int off = 1; off < 64; off <<= 1) {
        int u = __shfl_up(incl, off);
        if (lane >= off) incl += u;
    }
    __shared__ int wsum[4];
    if (lane == 63) wsum[w] = incl;
    __syncthreads();
    int woff = 0;
#pragma unroll
    for (int j = 0; j < 4; ++j)
        if (j < w) woff += wsum[j];
    if (i < N_NODES) ex[i] = woff + incl - v;
    if (t == 255) bsum[b] = woff + incl;
}

// single block scans the block sums (exclusive, in place); nb <= 128
__global__ __launch_bounds__(128) void scan2_k(int* __restrict__ bsum, int nb) {
    int t = threadIdx.x;
    int v = (t < nb) ? bsum[t] : 0;
    int lane = t & 63, w = t >> 6;
    int incl = v;
#pragma unroll
    for (int off = 1; off < 64; off <<= 1) {
        int u = __shfl_up(incl, off);
        if (lane >= off) incl += u;
    }
    __shared__ int wsum[2];
    if (lane == 63) wsum[w] = incl;
    __syncthreads();
    int woff = (w == 1) ? wsum[0] : 0;
    if (t < nb) bsum[t] = woff + incl - v;
}

// add block offsets; produce rowst, cursor, rowst[N]
__global__ __launch_bounds__(256) void scan3_k(const int* __restrict__ cnt,
                                               const int* __restrict__ bsum,
                                               int* __restrict__ rowst,
                                               int* __restrict__ cursor) {
    int b = blockIdx.x, t = threadIdx.x;
    int i = b * 256 + t;
    if (i < N_NODES) {
        int v = rowst[i] + bsum[b];
        rowst[i] = v;
        cursor[i] = v;
        if (i == N_NODES - 1) rowst[N_NODES] = v + cnt[i];
    }
}

// scatter edges into CSR order, permuting src and the 64B eattr row along.
// Conv loop then has only ONE indirect hop (hin[srcs[j]]) and a sequential
// eattrs stream.
__global__ void scatter_k(const int* __restrict__ src,
                          const int* __restrict__ dst,
                          const float* __restrict__ eattr,
                          int* __restrict__ cursor, int* __restrict__ srcs,
                          float* __restrict__ eattrs) {
    int e = blockIdx.x * blockDim.x + threadIdx.x;
    if (e < N_EDGES) {
        int pos = atomicAdd(&cursor[dst[e]], 1);
        srcs[pos] = src[e];
        const float4* a = (const float4*)(eattr + (size_t)e * FE);
        float4* o = (float4*)(eattrs + (size_t)pos * FE);
        o[0] = a[0];
        o[1] = a[1];
        o[2] = a[2];
        o[3] = a[3];
    }
}

// ---------------------------------------------------------------------------
// Repack node LSTM weights, INTERLEAVED: W2 row 2c = i-gate row c (node_W row
// c), W2 row 2c+1 = g-gate row c (node_W row 512+c). Same for bias. Makes
// (zi_c, zg_c) adjacent output columns so the GEMM epilogue fuses the LSTM
// activation (mode 3).
// ---------------------------------------------------------------------------
__global__ void repack_k(const float* __restrict__ W, const float* __restrict__ b,
                         float* __restrict__ W2, float* __restrict__ b2) {
    int idx = blockIdx.x * blockDim.x + threadIdx.x;
    if (idx < 512 * 64) {
        int r = idx >> 6, k = idx & 63;
        int c = r >> 1;
        int rs = (r & 1) ? (512 + c) : c;
        W2[idx] = W[rs * 64 + k];
    } else if (idx < 512 * 64 + 512) {
        int r = idx - 512 * 64;
        int c = r >> 1;
        int rs = (r & 1) ? (512 + c) : c;
        b2[r] = b[rs];
    }
}

// ---------------------------------------------------------------------------
// GENConv edge pass (gather form, softmax with m=0 shift).
// Thread = channel; edge-LSTM weights live in 32 VGPRs; no LDS, no barriers.
// ---------------------------------------------------------------------------
#define NPB 8
__global__ __launch_bounds__(256) void genconv_edge_k(
    const float* __restrict__ hin, const float* __restrict__ eattrs,
    const int* __restrict__ srcs, const int* __restrict__ rowst,
    const float* __restrict__ eW, const float* __restrict__ eb,
    const float* __restrict__ tptr, float* __restrict__ aout) {
    int tid = threadIdx.x;  // channel 0..255
    float wi[16], wg[16];
    const float4* Wi4 = (const float4*)(eW + (size_t)tid * FE);
    const float4* Wg4 = (const float4*)(eW + (size_t)(512 + tid) * FE);
#pragma unroll
    for (int q = 0; q < 4; ++q) {
        float4 a = Wi4[q], b = Wg4[q];
        wi[q * 4 + 0] = a.x; wi[q * 4 + 1] = a.y;
        wi[q * 4 + 2] = a.z; wi[q * 4 + 3] = a.w;
        wg[q * 4 + 0] = b.x; wg[q * 4 + 1] = b.y;
        wg[q * 4 + 2] = b.z; wg[q * 4 + 3] = b.w;
    }
    float bi = eb[tid], bg = eb[512 + tid];
    float tscale = tptr[0];
    int n0 = blockIdx.x * NPB;
    for (int u = 0; u < NPB; ++u) {
        int n = n0 + u;
        if (n >= N_NODES) break;
        int s0 = rowst[n], s1 = rowst[n + 1];
        float hself = hin[(size_t)n * HH + tid];
        float accE = 0.f, accWE = 0.f;
        for (int j = s0; j < s1; ++j) {
            int sn = srcs[j];  // uniform across block -> scalar load
            const float4* ap4 = (const float4*)(eattrs + (size_t)j * FE);
            float4 a0 = ap4[0], a1 = ap4[1], a2 = ap4[2], a3 = ap4[3];
            float av[16] = {a0.x, a0.y, a0.z, a0.w, a1.x, a1.y, a1.z, a1.w,
                            a2.x, a2.y, a2.z, a2.w, a3.x, a3.y, a3.z, a3.w};
            float zi = bi, zg = bg;
#pragma unroll
            for (int k = 0; k < FE; ++k) {
                zi += wi[k] * av[k];
                zg += wg[k] * av[k];
            }
            float eav = fast_sigmoid(zi) * fast_tanh(zg);
            float msg = fmaxf(hin[(size_t)sn * HH + tid] + eav, 0.f) + 1e-7f;
            float p = __expf(tscale * msg);
            accE += p;
            accWE += p * msg;
        }
        aout[(size_t)n * HH + tid] = hself + accWE / (accE + 1e-16f);
    }
}

// ---------------------------------------------------------------------------
// fp32 GEMM  C[M,NN] = A[M,K] @ B[NN,K]^T  ("NT", both K-contiguous)
// 128x128 tile, 256 threads, 8x8 microtile as 2x2 groups of 4x4 at stride 64.
// Register double-buffered staging: next tile's global loads issue before the
// compute loop so HBM/L2 latency hides under the 1024 FMAs.
// mode 0: y = relu((acc+bias)*gamma*rsqrt(1+1e-5) + beta)   (BN eval + relu)
// mode 1: y = relu(acc+bias)
// mode 2: y = acc+bias
// mode 3: LSTM fuse: out[m][n/2] = sigmoid(y0)*tanh(y1) pairs, C is [M, NN/2]
// ---------------------------------------------------------------------------
#define TM 128
#define TN 128
#define KB 16
__global__ __launch_bounds__(256) void gemm_nt_k(
    const float* __restrict__ A, const float* __restrict__ B,
    const float* __restrict__ bias, const float* __restrict__ gamma,
    const float* __restrict__ beta, float* __restrict__ C, int M, int NN,
    int K, int mode) {
    __shared__ float As[KB][TM + 4];
    __shared__ float Bs[KB][TN + 4];
    int tid = threadIdx.x;
    int row0 = blockIdx.x * TM, col0 = blockIdx.y * TN;
    int tx = tid & 15, ty = tid >> 4;
    int lr = tid >> 2;       // 0..63
    int lc = (tid & 3) * 4;  // 0,4,8,12
    float4 va[2], vb[2];
#pragma unroll
    for (int h = 0; h < 2; ++h) {
        int r = lr + h * 64;
        int gr = row0 + r;
        va[h] = (gr < M) ? *(const float4*)&A[(size_t)gr * K + lc]
                         : make_float4(0.f, 0.f, 0.f, 0.f);
        vb[h] = *(const float4*)&B[(size_t)(col0 + r) * K + lc];
    }
    float acc[8][8] = {{0.f}};
    for (int k0 = 0; k0 < K; k0 += KB) {
#pragma unroll
        for (int h = 0; h < 2; ++h) {
            int r = lr + h * 64;
            As[lc + 0][r] = va[h].x;
            As[lc + 1][r] = va[h].y;
            As[lc + 2][r] = va[h].z;
            As[lc + 3][r] = va[h].w;
            Bs[lc + 0][r] = vb[h].x;
            Bs[lc + 1][r] = vb[h].y;
            Bs[lc + 2][r] = vb[h].z;
            Bs[lc + 3][r] = vb[h].w;
        }
        __syncthreads();
        int k1 = k0 + KB;
        if (k1 < K) {
#pragma unroll
            for (int h = 0; h < 2; ++h) {
                int r = lr + h * 64;
                int gr = row0 + r;
                va[h] = (gr < M)
                            ? *(const float4*)&A[(size_t)gr * K + k1 + lc]
                            : make_float4(0.f, 0.f, 0.f, 0.f);
                vb[h] = *(const float4*)&B[(size_t)(col0 + r) * K + k1 + lc];
            }
        }
#pragma unroll
        for (int k = 0; k < KB; ++k) {
            float4 a0 = *(const float4*)&As[k][ty * 4];
            float4 a1 = *(const float4*)&As[k][64 + ty * 4];
            float4 b0 = *(const float4*)&Bs[k][tx * 4];
            float4 b1 = *(const float4*)&Bs[k][64 + tx * 4];
            float av[8] = {a0.x, a0.y, a0.z, a0.w, a1.x, a1.y, a1.z, a1.w};
            float bv[8] = {b0.x, b0.y, b0.z, b0.w, b1.x, b1.y, b1.z, b1.w};
#pragma unroll
            for (int i = 0; i < 8; ++i)
#pragma unroll
                for (int j = 0; j < 8; ++j) acc[i][j] += av[i] * bv[j];
        }
        __syncthreads();
    }
    const float bn_rs = rsqrtf(1.f + 1e-5f);
#pragma unroll
    for (int gj = 0; gj < 2; ++gj) {
        int nb = col0 + gj * 64 + tx * 4;
        float bs[4], sc[4], sh[4];
#pragma unroll
        for (int j = 0; j < 4; ++j) {
            bs[j] = bias[nb + j];
            if (mode == 0) {
                sc[j] = gamma[nb + j] * bn_rs;
                sh[j] = beta[nb + j];
            }
        }
#pragma unroll
        for (int gi = 0; gi < 2; ++gi) {
#pragma unroll
            for (int i2 = 0; i2 < 4; ++i2) {
                int m = row0 + gi * 64 + ty * 4 + i2;
                if (m >= M) continue;
                int i = gi * 4 + i2;
                float y[4];
#pragma unroll
                for (int j = 0; j < 4; ++j) {
                    float v = acc[i][gj * 4 + j] + bs[j];
                    if (mode == 0) v = v * sc[j] + sh[j];
                    if (mode == 0 || mode == 1) v = fmaxf(v, 0.f);
                    y[j] = v;
                }
                if (mode == 3) {
                    float2 o;
                    o.x = fast_sigmoid(y[0]) * fast_tanh(y[1]);
                    o.y = fast_sigmoid(y[2]) * fast_tanh(y[3]);
                    *(float2*)&C[(size_t)m * (NN / 2) + nb / 2] = o;
                } else {
                    float4 o = {y[0], y[1], y[2], y[3]};
                    *(float4*)&C[(size_t)m * NN + nb] = o;
                }
            }
        }
    }
}

// ---------------------------------------------------------------------------
// Instance norm over sorted batch segments (block = graph, thread = channel)
// ---------------------------------------------------------------------------
__device__ __forceinline__ int lowerb(const int* a, int n, int key) {
    int lo = 0, hi = n;
    while (lo < hi) {
        int mid = (lo + hi) >> 1;
        if (a[mid] < key) lo = mid + 1;
        else hi = mid;
    }
    return lo;
}

__global__ __launch_bounds__(256) void inst_norm_k(
    const float* __restrict__ x, const int* __restrict__ batch,
    float* __restrict__ y) {
    __shared__ int sS, sE;
    int g = blockIdx.x, t = threadIdx.x;
    if (t == 0) {
        sS = lowerb(batch, N_NODES, g);
        sE = lowerb(batch, N_NODES, g + 1);
    }
    __syncthreads();
    int s = sS, e = sE;
    float sum = 0.f, ss = 0.f;
    for (int n = s; n < e; ++n) {
        float v = x[(size_t)n * HH + t];
        sum += v;
        ss += v * v;
    }
    float c = (float)((e - s) > 0 ? (e - s) : 1);
    float mean = sum / c;
    float var = ss / c - mean * mean;
    float inv = rsqrtf(var + 1e-5f);
    for (int n = s; n < e; ++n) {
        float v = x[(size_t)n * HH + t];
        y[(size_t)n * HH + t] = (v - mean) * inv;
    }
}

// ---------------------------------------------------------------------------
// Fused: instance-norm + segment-max pool + linear + sigmoid (block = graph)
// ---------------------------------------------------------------------------
__global__ __launch_bounds__(256) void inpool_k(
    const float* __restrict__ x, const int* __restrict__ batch,
    const float* __restrict__ lw, const float* __restrict__ lb,
    float* __restrict__ out) {
    __shared__ float pooled[HH];
    __shared__ int sS, sE;
    int g = blockIdx.x, t = threadIdx.x;
    if (t == 0) {
        sS = lowerb(batch, N_NODES, g);
        sE = lowerb(batch, N_NODES, g + 1);
    }
    __syncthreads();
    int s = sS, e = sE;
    float sum = 0.f, ss = 0.f;
    for (int n = s; n < e; ++n) {
        float v = x[(size_t)n * HH + t];
        sum += v;
        ss += v * v;
    }
    float c = (float)((e - s) > 0 ? (e - s) : 1);
    float mean = sum / c;
    float var = ss / c - mean * mean;
    float inv = rsqrtf(var + 1e-5f);
    float m = -3.0e38f;
    for (int n = s; n < e; ++n) {
        float v = (x[(size_t)n * HH + t] - mean) * inv;
        m = fmaxf(m, v);
    }
    pooled[t] = (e > s) ? m : 0.f;
    __syncthreads();
    if (t < 10) {
        float acc = lb[t];
        for (int k = 0; k < HH; ++k) acc += pooled[k] * lw[t * HH + k];
        out[g * 10 + t] = fast_sigmoid(acc);
    }
}

// ---------------------------------------------------------------------------
extern "C" void kernel_launch(void* const* d_in, const int* in_sizes, int n_in,
                              void* d_out, int out_size, void* d_ws,
                              size_t ws_size, hipStream_t stream) {
    const float* x      = (const float*)d_in[0];
    const int*   ei     = (const int*)d_in[1];
    const float* eattr  = (const float*)d_in[2];
    const int*   batch  = (const int*)d_in[3];
    const float* nodeW  = (const float*)d_in[4];
    const float* nodeb  = (const float*)d_in[5];
    const float* edgeW  = (const float*)d_in[6];
    const float* edgeb  = (const float*)d_in[7];
    const float* t1     = (const float*)d_in[8];
    const float* g1w1   = (const float*)d_in[9];
    const float* g1b1   = (const float*)d_in[10];
    const float* g1g    = (const float*)d_in[11];
    const float* g1be   = (const float*)d_in[12];
    const float* g1w2   = (const float*)d_in[13];
    const float* g1b2   = (const float*)d_in[14];
    const float* t2     = (const float*)d_in[15];
    const float* g2w1   = (const float*)d_in[16];
    const float* g2b1   = (const float*)d_in[17];
    const float* g2g    = (const float*)d_in[18];
    const float* g2be   = (const float*)d_in[19];
    const float* g2w2   = (const float*)d_in[20];
    const float* g2b2   = (const float*)d_in[21];
    const float* linw   = (const float*)d_in[22];
    const float* linb   = (const float*)d_in[23];
    float* out = (float*)d_out;

    const int* srcA = ei;
    const int* dstA = ei + N_EDGES;

    // workspace layout (fp32), aliased:
    // F0 [N,256]: h0, then inst-norm-1 output (hin of conv2)
    // F1 [N,256]: conv aggr out / gemm2 out
    // F2 [N,512]: MLP mid
    float* F0 = (float*)d_ws;
    float* F1 = F0 + (size_t)N_NODES * HH;
    float* F2 = F1 + (size_t)N_NODES * HH;
    float* W2 = F2 + (size_t)N_NODES * 2 * HH;   // 512*64 interleaved
    float* b2 = W2 + 512 * 64;                   // 512
    float* eattrs = b2 + 512;                    // E*16, CSR-ordered
    int* cnt    = (int*)(eattrs + (size_t)N_EDGES * FE);
    int* cursor = cnt + N_NODES;
    int* rowst  = cursor + N_NODES;              // N+1
    int* srcs   = rowst + N_NODES + 1;           // E, CSR-ordered
    int* bsum   = srcs + N_EDGES;                // 128

    const int NSCB = (N_NODES + 255) / 256;      // 79

    // --- CSR build ---
    hipMemsetAsync(cnt, 0, N_NODES * sizeof(int), stream);
    hist_k<<<(N_EDGES + 255) / 256, 256, 0, stream>>>(dstA, cnt);
    scan1_k<<<NSCB, 256, 0, stream>>>(cnt, rowst, bsum);
    scan2_k<<<1, 128, 0, stream>>>(bsum, NSCB);
    scan3_k<<<NSCB, 256, 0, stream>>>(cnt, bsum, rowst, cursor);
    scatter_k<<<(N_EDGES + 255) / 256, 256, 0, stream>>>(srcA, dstA, eattr,
                                                         cursor, srcs, eattrs);

    // --- node LSTM: repack (interleaved) -> GEMM with fused activation ---
    repack_k<<<(512 * 64 + 512 + 255) / 256, 256, 0, stream>>>(nodeW, nodeb,
                                                               W2, b2);
    dim3 gemm_grid1((N_NODES + TM - 1) / TM, 512 / TN);
    dim3 gemm_grid2((N_NODES + TM - 1) / TM, 256 / TN);
    gemm_nt_k<<<gemm_grid1, 256, 0, stream>>>(x, W2, b2, nullptr, nullptr, F0,
                                              N_NODES, 512, 64, 3);

    // --- GENConv 1 ---
    genconv_edge_k<<<(N_NODES + NPB - 1) / NPB, 256, 0, stream>>>(
        F0, eattrs, srcs, rowst, edgeW, edgeb, t1, F1);
    gemm_nt_k<<<gemm_grid1, 256, 0, stream>>>(F1, g1w1, g1b1, g1g, g1be, F2,
                                              N_NODES, 512, 256, 0);
    gemm_nt_k<<<gemm_grid2, 256, 0, stream>>>(F2, g1w2, g1b2, nullptr, nullptr,
                                              F1, N_NODES, 256, 512, 1);
    inst_norm_k<<<GG, 256, 0, stream>>>(F1, batch, F0);

    // --- GENConv 2 ---
    genconv_edge_k<<<(N_NODES + NPB - 1) / NPB, 256, 0, stream>>>(
        F0, eattrs, srcs, rowst, edgeW, edgeb, t2, F1);
    gemm_nt_k<<<gemm_grid1, 256, 0, stream>>>(F1, g2w1, g2b1, g2g, g2be, F2,
                                              N_NODES, 512, 256, 0);
    gemm_nt_k<<<gemm_grid2, 256, 0, stream>>>(F2, g2w2, g2b2, nullptr, nullptr,
                                              F1, N_NODES, 256, 512, 1);

    // --- fused inst-norm + pool + linear + sigmoid ---
    inpool_k<<<GG, 256, 0, stream>>>(F1, batch, linw, linb, out);
}

// Round 5
// 985.603 us; speedup vs baseline: 1.1015x; 1.1015x over previous
//
#include <hip/hip_runtime.h>
#include <math.h>

#define N_NODES 20000
#define N_EDGES 320000
#define HH      256
#define GG      128
#define FN      64
#define FE      16

__device__ __forceinline__ float fast_rcp(float x) {
    return __builtin_amdgcn_rcpf(x);
}
__device__ __forceinline__ float fast_sigmoid(float x) {
    return fast_rcp(1.f + __expf(-x));
}
// sigmoid(zi)*tanh(zg) with 3 transcendental + 1 rcp
__device__ __forceinline__ float sig_tanh(float zi, float zg) {
    float u = __expf(-zi);          // sigmoid = 1/(1+u)
    float v = __expf(2.f * zg);     // tanh = (v-1)/(v+1)
    return (v - 1.f) * fast_rcp((1.f + u) * (v + 1.f));
}

// ---------------------------------------------------------------------------
// CSR build: histogram / two-level scan / permuting scatter
// ---------------------------------------------------------------------------
__global__ void hist_k(const int* __restrict__ dst, int* __restrict__ cnt) {
    int e = blockIdx.x * blockDim.x + threadIdx.x;
    if (e < N_EDGES) atomicAdd(&cnt[dst[e]], 1);
}

__global__ __launch_bounds__(256) void scan1_k(const int* __restrict__ cnt,
                                               int* __restrict__ ex,
                                               int* __restrict__ bsum) {
    int b = blockIdx.x, t = threadIdx.x;
    int i = b * 256 + t;
    int v = (i < N_NODES) ? cnt[i] : 0;
    int lane = t & 63, w = t >> 6;
    int incl = v;
#pragma unroll
    for (int off = 1; off < 64; off <<= 1) {
        int u = __shfl_up(incl, off);
        if (lane >= off) incl += u;
    }
    __shared__ int wsum[4];
    if (lane == 63) wsum[w] = incl;
    __syncthreads();
    int woff = 0;
#pragma unroll
    for (int j = 0; j < 4; ++j)
        if (j < w) woff += wsum[j];
    if (i < N_NODES) ex[i] = woff + incl - v;
    if (t == 255) bsum[b] = woff + incl;
}

__global__ __launch_bounds__(128) void scan2_k(int* __restrict__ bsum, int nb) {
    int t = threadIdx.x;
    int v = (t < nb) ? bsum[t] : 0;
    int lane = t & 63, w = t >> 6;
    int incl = v;
#pragma unroll
    for (int off = 1; off < 64; off <<= 1) {
        int u = __shfl_up(incl, off);
        if (lane >= off) incl += u;
    }
    __shared__ int wsum[2];
    if (lane == 63) wsum[w] = incl;
    __syncthreads();
    int woff = (w == 1) ? wsum[0] : 0;
    if (t < nb) bsum[t] = woff + incl - v;
}

__global__ __launch_bounds__(256) void scan3_k(const int* __restrict__ cnt,
                                               const int* __restrict__ bsum,
                                               int* __restrict__ rowst,
                                               int* __restrict__ cursor) {
    int b = blockIdx.x, t = threadIdx.x;
    int i = b * 256 + t;
    if (i < N_NODES) {
        int v = rowst[i] + bsum[b];
        rowst[i] = v;
        cursor[i] = v;
        if (i == N_NODES - 1) rowst[N_NODES] = v + cnt[i];
    }
}

// scatter edges into CSR order, permuting src and the 64B eattr row along
__global__ void scatter_k(const int* __restrict__ src,
                          const int* __restrict__ dst,
                          const float* __restrict__ eattr,
                          int* __restrict__ cursor, int* __restrict__ srcs,
                          float* __restrict__ eattrs) {
    int e = blockIdx.x * blockDim.x + threadIdx.x;
    if (e < N_EDGES) {
        int pos = atomicAdd(&cursor[dst[e]], 1);
        srcs[pos] = src[e];
        const float4* a = (const float4*)(eattr + (size_t)e * FE);
        float4* o = (float4*)(eattrs + (size_t)pos * FE);
        o[0] = a[0];
        o[1] = a[1];
        o[2] = a[2];
        o[3] = a[3];
    }
}

// ---------------------------------------------------------------------------
// Repack node LSTM weights, INTERLEAVED (i/g rows adjacent) for the fused
// LSTM-activation GEMM epilogue (mode 3).
// ---------------------------------------------------------------------------
__global__ void repack_k(const float* __restrict__ W, const float* __restrict__ b,
                         float* __restrict__ W2, float* __restrict__ b2) {
    int idx = blockIdx.x * blockDim.x + threadIdx.x;
    if (idx < 512 * 64) {
        int r = idx >> 6, k = idx & 63;
        int c = r >> 1;
        int rs = (r & 1) ? (512 + c) : c;
        W2[idx] = W[rs * 64 + k];
    } else if (idx < 512 * 64 + 512) {
        int r = idx - 512 * 64;
        int c = r >> 1;
        int rs = (r & 1) ? (512 + c) : c;
        b2[r] = b[rs];
    }
}

// ---------------------------------------------------------------------------
// GENConv edge pass (gather form, softmax with m=0 shift).
// Thread = channel; edge-LSTM weights in VGPRs. __launch_bounds__(256,4)
// gives the allocator ~128 VGPRs/wave (16 waves/CU) so the 48 weight/attr
// floats actually stay register-resident (r4 showed VGPR_Count=32 => bloat).
// 2-way unrolled with independent accumulators for ILP.
// ---------------------------------------------------------------------------
#define NPB 8
__global__ __launch_bounds__(256, 4) void genconv_edge_k(
    const float* __restrict__ hin, const float* __restrict__ eattrs,
    const int* __restrict__ srcs, const int* __restrict__ rowst,
    const float* __restrict__ eW, const float* __restrict__ eb,
    const float* __restrict__ tptr, float* __restrict__ aout) {
    int tid = threadIdx.x;  // channel 0..255
    float wi[16], wg[16];
    const float4* Wi4 = (const float4*)(eW + (size_t)tid * FE);
    const float4* Wg4 = (const float4*)(eW + (size_t)(512 + tid) * FE);
#pragma unroll
    for (int q = 0; q < 4; ++q) {
        float4 a = Wi4[q], b = Wg4[q];
        wi[q * 4 + 0] = a.x; wi[q * 4 + 1] = a.y;
        wi[q * 4 + 2] = a.z; wi[q * 4 + 3] = a.w;
        wg[q * 4 + 0] = b.x; wg[q * 4 + 1] = b.y;
        wg[q * 4 + 2] = b.z; wg[q * 4 + 3] = b.w;
    }
    float bi = eb[tid], bg = eb[512 + tid];
    float tscale = tptr[0];
    int n0 = blockIdx.x * NPB;
    for (int u = 0; u < NPB; ++u) {
        int n = n0 + u;
        if (n >= N_NODES) break;
        int s0 = rowst[n], s1 = rowst[n + 1];
        float hself = hin[(size_t)n * HH + tid];
        float accE0 = 0.f, accWE0 = 0.f, accE1 = 0.f, accWE1 = 0.f;
        int j = s0;
        for (; j + 1 < s1; j += 2) {
            int sn0 = srcs[j], sn1 = srcs[j + 1];
            const float4* ap0 = (const float4*)(eattrs + (size_t)j * FE);
            const float4* ap1 = (const float4*)(eattrs + (size_t)(j + 1) * FE);
            float4 a0 = ap0[0], a1 = ap0[1], a2 = ap0[2], a3 = ap0[3];
            float4 c0 = ap1[0], c1 = ap1[1], c2 = ap1[2], c3 = ap1[3];
            float h0v = hin[(size_t)sn0 * HH + tid];
            float h1v = hin[(size_t)sn1 * HH + tid];
            float av[16] = {a0.x, a0.y, a0.z, a0.w, a1.x, a1.y, a1.z, a1.w,
                            a2.x, a2.y, a2.z, a2.w, a3.x, a3.y, a3.z, a3.w};
            float cv[16] = {c0.x, c0.y, c0.z, c0.w, c1.x, c1.y, c1.z, c1.w,
                            c2.x, c2.y, c2.z, c2.w, c3.x, c3.y, c3.z, c3.w};
            float zi0 = bi, zg0 = bg, zi1 = bi, zg1 = bg;
#pragma unroll
            for (int k = 0; k < FE; ++k) {
                zi0 += wi[k] * av[k];
                zg0 += wg[k] * av[k];
                zi1 += wi[k] * cv[k];
                zg1 += wg[k] * cv[k];
            }
            float ea0 = sig_tanh(zi0, zg0);
            float ea1 = sig_tanh(zi1, zg1);
            float m0 = fmaxf(h0v + ea0, 0.f) + 1e-7f;
            float m1 = fmaxf(h1v + ea1, 0.f) + 1e-7f;
            float p0 = __expf(tscale * m0);
            float p1 = __expf(tscale * m1);
            accE0 += p0;
            accWE0 += p0 * m0;
            accE1 += p1;
            accWE1 += p1 * m1;
        }
        if (j < s1) {
            int sn = srcs[j];
            const float4* ap = (const float4*)(eattrs + (size_t)j * FE);
            float4 a0 = ap[0], a1 = ap[1], a2 = ap[2], a3 = ap[3];
            float hv = hin[(size_t)sn * HH + tid];
            float av[16] = {a0.x, a0.y, a0.z, a0.w, a1.x, a1.y, a1.z, a1.w,
                            a2.x, a2.y, a2.z, a2.w, a3.x, a3.y, a3.z, a3.w};
            float zi = bi, zg = bg;
#pragma unroll
            for (int k = 0; k < FE; ++k) {
                zi += wi[k] * av[k];
                zg += wg[k] * av[k];
            }
            float eav = sig_tanh(zi, zg);
            float m0 = fmaxf(hv + eav, 0.f) + 1e-7f;
            float p0 = __expf(tscale * m0);
            accE0 += p0;
            accWE0 += p0 * m0;
        }
        float accE = accE0 + accE1, accWE = accWE0 + accWE1;
        aout[(size_t)n * HH + tid] = hself + accWE / (accE + 1e-16f);
    }
}

// ---------------------------------------------------------------------------
// fp32 GEMM  C[M,NN] = A[M,K] @ B[NN,K]^T  ("NT")
// 128x128 tile, 256 threads, 8x8 microtile (2x2 groups of 4x4 at stride 64),
// register double-buffered staging.
// mode 0: relu(BN(acc+bias)); mode 1: relu(acc+bias); mode 2: acc+bias;
// mode 3: LSTM fuse sigmoid(y0)*tanh(y1), C is [M, NN/2]
// ---------------------------------------------------------------------------
#define TM 128
#define TN 128
#define KB 16
__global__ __launch_bounds__(256, 2) void gemm_nt_k(
    const float* __restrict__ A, const float* __restrict__ B,
    const float* __restrict__ bias, const float* __restrict__ gamma,
    const float* __restrict__ beta, float* __restrict__ C, int M, int NN,
    int K, int mode) {
    __shared__ float As[KB][TM + 4];
    __shared__ float Bs[KB][TN + 4];
    int tid = threadIdx.x;
    int row0 = blockIdx.x * TM, col0 = blockIdx.y * TN;
    int tx = tid & 15, ty = tid >> 4;
    int lr = tid >> 2;       // 0..63
    int lc = (tid & 3) * 4;  // 0,4,8,12
    float4 va[2], vb[2];
#pragma unroll
    for (int h = 0; h < 2; ++h) {
        int r = lr + h * 64;
        int gr = row0 + r;
        va[h] = (gr < M) ? *(const float4*)&A[(size_t)gr * K + lc]
                         : make_float4(0.f, 0.f, 0.f, 0.f);
        vb[h] = *(const float4*)&B[(size_t)(col0 + r) * K + lc];
    }
    float acc[8][8] = {{0.f}};
    for (int k0 = 0; k0 < K; k0 += KB) {
#pragma unroll
        for (int h = 0; h < 2; ++h) {
            int r = lr + h * 64;
            As[lc + 0][r] = va[h].x;
            As[lc + 1][r] = va[h].y;
            As[lc + 2][r] = va[h].z;
            As[lc + 3][r] = va[h].w;
            Bs[lc + 0][r] = vb[h].x;
            Bs[lc + 1][r] = vb[h].y;
            Bs[lc + 2][r] = vb[h].z;
            Bs[lc + 3][r] = vb[h].w;
        }
        __syncthreads();
        int k1 = k0 + KB;
        if (k1 < K) {
#pragma unroll
            for (int h = 0; h < 2; ++h) {
                int r = lr + h * 64;
                int gr = row0 + r;
                va[h] = (gr < M)
                            ? *(const float4*)&A[(size_t)gr * K + k1 + lc]
                            : make_float4(0.f, 0.f, 0.f, 0.f);
                vb[h] = *(const float4*)&B[(size_t)(col0 + r) * K + k1 + lc];
            }
        }
#pragma unroll
        for (int k = 0; k < KB; ++k) {
            float4 a0 = *(const float4*)&As[k][ty * 4];
            float4 a1 = *(const float4*)&As[k][64 + ty * 4];
            float4 b0 = *(const float4*)&Bs[k][tx * 4];
            float4 b1 = *(const float4*)&Bs[k][64 + tx * 4];
            float av[8] = {a0.x, a0.y, a0.z, a0.w, a1.x, a1.y, a1.z, a1.w};
            float bv[8] = {b0.x, b0.y, b0.z, b0.w, b1.x, b1.y, b1.z, b1.w};
#pragma unroll
            for (int i = 0; i < 8; ++i)
#pragma unroll
                for (int j = 0; j < 8; ++j) acc[i][j] += av[i] * bv[j];
        }
        __syncthreads();
    }
    const float bn_rs = rsqrtf(1.f + 1e-5f);
#pragma unroll
    for (int gj = 0; gj < 2; ++gj) {
        int nb = col0 + gj * 64 + tx * 4;
        float bs[4], sc[4], sh[4];
#pragma unroll
        for (int j = 0; j < 4; ++j) {
            bs[j] = bias[nb + j];
            if (mode == 0) {
                sc[j] = gamma[nb + j] * bn_rs;
                sh[j] = beta[nb + j];
            }
        }
#pragma unroll
        for (int gi = 0; gi < 2; ++gi) {
#pragma unroll
            for (int i2 = 0; i2 < 4; ++i2) {
                int m = row0 + gi * 64 + ty * 4 + i2;
                if (m >= M) continue;
                int i = gi * 4 + i2;
                float y[4];
#pragma unroll
                for (int j = 0; j < 4; ++j) {
                    float v = acc[i][gj * 4 + j] + bs[j];
                    if (mode == 0) v = v * sc[j] + sh[j];
                    if (mode == 0 || mode == 1) v = fmaxf(v, 0.f);
                    y[j] = v;
                }
                if (mode == 3) {
                    float2 o;
                    o.x = sig_tanh(y[0], y[1]);
                    o.y = sig_tanh(y[2], y[3]);
                    *(float2*)&C[(size_t)m * (NN / 2) + nb / 2] = o;
                } else {
                    float4 o = {y[0], y[1], y[2], y[3]};
                    *(float4*)&C[(size_t)m * NN + nb] = o;
                }
            }
        }
    }
}

// ---------------------------------------------------------------------------
// Instance norm over sorted batch segments (block = graph, thread = channel)
// ---------------------------------------------------------------------------
__device__ __forceinline__ int lowerb(const int* a, int n, int key) {
    int lo = 0, hi = n;
    while (lo < hi) {
        int mid = (lo + hi) >> 1;
        if (a[mid] < key) lo = mid + 1;
        else hi = mid;
    }
    return lo;
}

__global__ __launch_bounds__(256) void inst_norm_k(
    const float* __restrict__ x, const int* __restrict__ batch,
    float* __restrict__ y) {
    __shared__ int sS, sE;
    int g = blockIdx.x, t = threadIdx.x;
    if (t == 0) {
        sS = lowerb(batch, N_NODES, g);
        sE = lowerb(batch, N_NODES, g + 1);
    }
    __syncthreads();
    int s = sS, e = sE;
    float sum = 0.f, ss = 0.f;
    for (int n = s; n < e; ++n) {
        float v = x[(size_t)n * HH + t];
        sum += v;
        ss += v * v;
    }
    float c = (float)((e - s) > 0 ? (e - s) : 1);
    float mean = sum / c;
    float var = ss / c - mean * mean;
    float inv = rsqrtf(var + 1e-5f);
    for (int n = s; n < e; ++n) {
        float v = x[(size_t)n * HH + t];
        y[(size_t)n * HH + t] = (v - mean) * inv;
    }
}

// ---------------------------------------------------------------------------
// Fused: instance-norm + segment-max pool + linear + sigmoid (block = graph)
// ---------------------------------------------------------------------------
__global__ __launch_bounds__(256) void inpool_k(
    const float* __restrict__ x, const int* __restrict__ batch,
    const float* __restrict__ lw, const float* __restrict__ lb,
    float* __restrict__ out) {
    __shared__ float pooled[HH];
    __shared__ int sS, sE;
    int g = blockIdx.x, t = threadIdx.x;
    if (t == 0) {
        sS = lowerb(batch, N_NODES, g);
        sE = lowerb(batch, N_NODES, g + 1);
    }
    __syncthreads();
    int s = sS, e = sE;
    float sum = 0.f, ss = 0.f;
    for (int n = s; n < e; ++n) {
        float v = x[(size_t)n * HH + t];
        sum += v;
        ss += v * v;
    }
    float c = (float)((e - s) > 0 ? (e - s) : 1);
    float mean = sum / c;
    float var = ss / c - mean * mean;
    float inv = rsqrtf(var + 1e-5f);
    float m = -3.0e38f;
    for (int n = s; n < e; ++n) {
        float v = (x[(size_t)n * HH + t] - mean) * inv;
        m = fmaxf(m, v);
    }
    pooled[t] = (e > s) ? m : 0.f;
    __syncthreads();
    if (t < 10) {
        float acc = lb[t];
        for (int k = 0; k < HH; ++k) acc += pooled[k] * lw[t * HH + k];
        out[g * 10 + t] = fast_sigmoid(acc);
    }
}

// ---------------------------------------------------------------------------
extern "C" void kernel_launch(void* const* d_in, const int* in_sizes, int n_in,
                              void* d_out, int out_size, void* d_ws,
                              size_t ws_size, hipStream_t stream) {
    const float* x      = (const float*)d_in[0];
    const int*   ei     = (const int*)d_in[1];
    const float* eattr  = (const float*)d_in[2];
    const int*   batch  = (const int*)d_in[3];
    const float* nodeW  = (const float*)d_in[4];
    const float* nodeb  = (const float*)d_in[5];
    const float* edgeW  = (const float*)d_in[6];
    const float* edgeb  = (const float*)d_in[7];
    const float* t1     = (const float*)d_in[8];
    const float* g1w1   = (const float*)d_in[9];
    const float* g1b1   = (const float*)d_in[10];
    const float* g1g    = (const float*)d_in[11];
    const float* g1be   = (const float*)d_in[12];
    const float* g1w2   = (const float*)d_in[13];
    const float* g1b2   = (const float*)d_in[14];
    const float* t2     = (const float*)d_in[15];
    const float* g2w1   = (const float*)d_in[16];
    const float* g2b1   = (const float*)d_in[17];
    const float* g2g    = (const float*)d_in[18];
    const float* g2be   = (const float*)d_in[19];
    const float* g2w2   = (const float*)d_in[20];
    const float* g2b2   = (const float*)d_in[21];
    const float* linw   = (const float*)d_in[22];
    const float* linb   = (const float*)d_in[23];
    float* out = (float*)d_out;

    const int* srcA = ei;
    const int* dstA = ei + N_EDGES;

    float* F0 = (float*)d_ws;                    // [N,256]
    float* F1 = F0 + (size_t)N_NODES * HH;       // [N,256]
    float* F2 = F1 + (size_t)N_NODES * HH;       // [N,512]
    float* W2 = F2 + (size_t)N_NODES * 2 * HH;   // 512*64 interleaved
    float* b2 = W2 + 512 * 64;                   // 512
    float* eattrs = b2 + 512;                    // E*16, CSR-ordered
    int* cnt    = (int*)(eattrs + (size_t)N_EDGES * FE);
    int* cursor = cnt + N_NODES;
    int* rowst  = cursor + N_NODES;              // N+1
    int* srcs   = rowst + N_NODES + 1;           // E, CSR-ordered
    int* bsum   = srcs + N_EDGES;                // 128

    const int NSCB = (N_NODES + 255) / 256;      // 79

    // --- CSR build ---
    hipMemsetAsync(cnt, 0, N_NODES * sizeof(int), stream);
    hist_k<<<(N_EDGES + 255) / 256, 256, 0, stream>>>(dstA, cnt);
    scan1_k<<<NSCB, 256, 0, stream>>>(cnt, rowst, bsum);
    scan2_k<<<1, 128, 0, stream>>>(bsum, NSCB);
    scan3_k<<<NSCB, 256, 0, stream>>>(cnt, bsum, rowst, cursor);
    scatter_k<<<(N_EDGES + 255) / 256, 256, 0, stream>>>(srcA, dstA, eattr,
                                                         cursor, srcs, eattrs);

    // --- node LSTM: repack (interleaved) -> GEMM with fused activation ---
    repack_k<<<(512 * 64 + 512 + 255) / 256, 256, 0, stream>>>(nodeW, nodeb,
                                                               W2, b2);
    dim3 gemm_grid1((N_NODES + TM - 1) / TM, 512 / TN);
    dim3 gemm_grid2((N_NODES + TM - 1) / TM, 256 / TN);
    gemm_nt_k<<<gemm_grid1, 256, 0, stream>>>(x, W2, b2, nullptr, nullptr, F0,
                                              N_NODES, 512, 64, 3);

    // --- GENConv 1 ---
    genconv_edge_k<<<(N_NODES + NPB - 1) / NPB, 256, 0, stream>>>(
        F0, eattrs, srcs, rowst, edgeW, edgeb, t1, F1);
    gemm_nt_k<<<gemm_grid1, 256, 0, stream>>>(F1, g1w1, g1b1, g1g, g1be, F2,
                                              N_NODES, 512, 256, 0);
    gemm_nt_k<<<gemm_grid2, 256, 0, stream>>>(F2, g1w2, g1b2, nullptr, nullptr,
                                              F1, N_NODES, 256, 512, 1);
    inst_norm_k<<<GG, 256, 0, stream>>>(F1, batch, F0);

    // --- GENConv 2 ---
    genconv_edge_k<<<(N_NODES + NPB - 1) / NPB, 256, 0, stream>>>(
        F0, eattrs, srcs, rowst, edgeW, edgeb, t2, F1);
    gemm_nt_k<<<gemm_grid1, 256, 0, stream>>>(F1, g2w1, g2b1, g2g, g2be, F2,
                                              N_NODES, 512, 256, 0);
    gemm_nt_k<<<gemm_grid2, 256, 0, stream>>>(F2, g2w2, g2b2, nullptr, nullptr,
                                              F1, N_NODES, 256, 512, 1);

    // --- fused inst-norm + pool + linear + sigmoid ---
    inpool_k<<<GG, 256, 0, stream>>>(F1, batch, linw, linb, out);
}

// Round 6
// 978.747 us; speedup vs baseline: 1.1092x; 1.0070x over previous
//
#include <hip/hip_runtime.h>
#include <hip/hip_bf16.h>
#include <math.h>

#define N_NODES 20000
#define N_EDGES 320000
#define HH      256
#define GG      128
#define FN      64
#define FE      16

__device__ __forceinline__ float fast_rcp(float x) {
    return __builtin_amdgcn_rcpf(x);
}
__device__ __forceinline__ float fast_sigmoid(float x) {
    return fast_rcp(1.f + __expf(-x));
}
// sigmoid(zi)*tanh(zg) with 2 transcendental + 1 rcp
__device__ __forceinline__ float sig_tanh(float zi, float zg) {
    float u = __expf(-zi);          // sigmoid = 1/(1+u)
    float v = __expf(2.f * zg);     // tanh = (v-1)/(v+1)
    return (v - 1.f) * fast_rcp((1.f + u) * (v + 1.f));
}

// ---------------------------------------------------------------------------
// CSR build: histogram / two-level scan / permuting scatter
// ---------------------------------------------------------------------------
__global__ void hist_k(const int* __restrict__ dst, int* __restrict__ cnt) {
    int e = blockIdx.x * blockDim.x + threadIdx.x;
    if (e < N_EDGES) atomicAdd(&cnt[dst[e]], 1);
}

__global__ __launch_bounds__(256) void scan1_k(const int* __restrict__ cnt,
                                               int* __restrict__ ex,
                                               int* __restrict__ bsum) {
    int b = blockIdx.x, t = threadIdx.x;
    int i = b * 256 + t;
    int v = (i < N_NODES) ? cnt[i] : 0;
    int lane = t & 63, w = t >> 6;
    int incl = v;
#pragma unroll
    for (int off = 1; off < 64; off <<= 1) {
        int u = __shfl_up(incl, off);
        if (lane >= off) incl += u;
    }
    __shared__ int wsum[4];
    if (lane == 63) wsum[w] = incl;
    __syncthreads();
    int woff = 0;
#pragma unroll
    for (int j = 0; j < 4; ++j)
        if (j < w) woff += wsum[j];
    if (i < N_NODES) ex[i] = woff + incl - v;
    if (t == 255) bsum[b] = woff + incl;
}

__global__ __launch_bounds__(128) void scan2_k(int* __restrict__ bsum, int nb) {
    int t = threadIdx.x;
    int v = (t < nb) ? bsum[t] : 0;
    int lane = t & 63, w = t >> 6;
    int incl = v;
#pragma unroll
    for (int off = 1; off < 64; off <<= 1) {
        int u = __shfl_up(incl, off);
        if (lane >= off) incl += u;
    }
    __shared__ int wsum[2];
    if (lane == 63) wsum[w] = incl;
    __syncthreads();
    int woff = (w == 1) ? wsum[0] : 0;
    if (t < nb) bsum[t] = woff + incl - v;
}

__global__ __launch_bounds__(256) void scan3_k(const int* __restrict__ cnt,
                                               const int* __restrict__ bsum,
                                               int* __restrict__ rowst,
                                               int* __restrict__ cursor) {
    int b = blockIdx.x, t = threadIdx.x;
    int i = b * 256 + t;
    if (i < N_NODES) {
        int v = rowst[i] + bsum[b];
        rowst[i] = v;
        cursor[i] = v;
        if (i == N_NODES - 1) rowst[N_NODES] = v + cnt[i];
    }
}

// scatter edges into CSR order, permuting src and the 64B eattr row along
__global__ void scatter_k(const int* __restrict__ src,
                          const int* __restrict__ dst,
                          const float* __restrict__ eattr,
                          int* __restrict__ cursor, int* __restrict__ srcs,
                          float* __restrict__ eattrs) {
    int e = blockIdx.x * blockDim.x + threadIdx.x;
    if (e < N_EDGES) {
        int pos = atomicAdd(&cursor[dst[e]], 1);
        srcs[pos] = src[e];
        const float4* a = (const float4*)(eattr + (size_t)e * FE);
        float4* o = (float4*)(eattrs + (size_t)pos * FE);
        o[0] = a[0];
        o[1] = a[1];
        o[2] = a[2];
        o[3] = a[3];
    }
}

// ---------------------------------------------------------------------------
// Repack LSTM weights, INTERLEAVED: W2 row 2c = i-gate row c (W row c),
// W2 row 2c+1 = g-gate row c (W row 512+c). K = input width (64 node,
// 16 edge). Makes (zi_c, zg_c) adjacent output columns so the GEMM epilogue
// fuses the LSTM activation (modes 3/4).
// ---------------------------------------------------------------------------
__global__ void repack_k(const float* __restrict__ W, const float* __restrict__ b,
                         float* __restrict__ W2, float* __restrict__ b2, int K) {
    int idx = blockIdx.x * blockDim.x + threadIdx.x;
    if (idx < 512 * K) {
        int r = idx / K, k = idx - r * K;
        int c = r >> 1;
        int rs = (r & 1) ? (512 + c) : c;
        W2[idx] = W[rs * K + k];
    } else if (idx < 512 * K + 512) {
        int r = idx - 512 * K;
        int c = r >> 1;
        int rs = (r & 1) ? (512 + c) : c;
        b2[r] = b[rs];
    }
}

// ---------------------------------------------------------------------------
// GENConv edge pass (gather form, softmax with m=0 shift).
// Edge-LSTM is PRE-COMPUTED into eacsr (bf16, CSR-ordered) by a GEMM; this
// loop is now ~8 VALU ops + 2 loads per edge-channel.
// ---------------------------------------------------------------------------
#define NPB 8
__global__ __launch_bounds__(256, 8) void genconv_edge_k(
    const float* __restrict__ hin, const __hip_bfloat16* __restrict__ eacsr,
    const int* __restrict__ srcs, const int* __restrict__ rowst,
    const float* __restrict__ tptr, float* __restrict__ aout) {
    int tid = threadIdx.x;  // channel 0..255
    float tscale = tptr[0];
    int n0 = blockIdx.x * NPB;
    for (int u = 0; u < NPB; ++u) {
        int n = n0 + u;
        if (n >= N_NODES) break;
        int s0 = rowst[n], s1 = rowst[n + 1];
        float hself = hin[(size_t)n * HH + tid];
        float accE0 = 0.f, accWE0 = 0.f, accE1 = 0.f, accWE1 = 0.f;
        int j = s0;
        for (; j + 1 < s1; j += 2) {
            int sn0 = srcs[j], sn1 = srcs[j + 1];
            float ea0 = __bfloat162float(eacsr[(size_t)j * HH + tid]);
            float ea1 = __bfloat162float(eacsr[(size_t)(j + 1) * HH + tid]);
            float h0v = hin[(size_t)sn0 * HH + tid];
            float h1v = hin[(size_t)sn1 * HH + tid];
            float m0 = fmaxf(h0v + ea0, 0.f) + 1e-7f;
            float m1 = fmaxf(h1v + ea1, 0.f) + 1e-7f;
            float p0 = __expf(tscale * m0);
            float p1 = __expf(tscale * m1);
            accE0 += p0;
            accWE0 += p0 * m0;
            accE1 += p1;
            accWE1 += p1 * m1;
        }
        if (j < s1) {
            int sn = srcs[j];
            float eav = __bfloat162float(eacsr[(size_t)j * HH + tid]);
            float hv = hin[(size_t)sn * HH + tid];
            float m0 = fmaxf(hv + eav, 0.f) + 1e-7f;
            float p0 = __expf(tscale * m0);
            accE0 += p0;
            accWE0 += p0 * m0;
        }
        float accE = accE0 + accE1, accWE = accWE0 + accWE1;
        aout[(size_t)n * HH + tid] = hself + accWE / (accE + 1e-16f);
    }
}

// ---------------------------------------------------------------------------
// fp32 GEMM  C[M,NN] = A[M,K] @ B[NN,K]^T  ("NT")
// 128x128 tile, 256 threads, 8x8 microtile (2x2 groups of 4x4 at stride 64),
// register double-buffered staging.
// mode 0: relu(BN(acc+bias)); mode 1: relu(acc+bias); mode 2: acc+bias;
// mode 3: LSTM fuse sigmoid(y0)*tanh(y1) -> fp32, C is [M, NN/2]
// mode 4: LSTM fuse -> bf16, C is [M, NN/2] bf16
// ---------------------------------------------------------------------------
#define TM 128
#define TN 128
#define KB 16
__global__ __launch_bounds__(256, 2) void gemm_nt_k(
    const float* __restrict__ A, const float* __restrict__ B,
    const float* __restrict__ bias, const float* __restrict__ gamma,
    const float* __restrict__ beta, float* __restrict__ C, int M, int NN,
    int K, int mode) {
    __shared__ float As[KB][TM + 4];
    __shared__ float Bs[KB][TN + 4];
    int tid = threadIdx.x;
    int row0 = blockIdx.x * TM, col0 = blockIdx.y * TN;
    int tx = tid & 15, ty = tid >> 4;
    int lr = tid >> 2;       // 0..63
    int lc = (tid & 3) * 4;  // 0,4,8,12
    float4 va[2], vb[2];
#pragma unroll
    for (int h = 0; h < 2; ++h) {
        int r = lr + h * 64;
        int gr = row0 + r;
        va[h] = (gr < M) ? *(const float4*)&A[(size_t)gr * K + lc]
                         : make_float4(0.f, 0.f, 0.f, 0.f);
        vb[h] = *(const float4*)&B[(size_t)(col0 + r) * K + lc];
    }
    float acc[8][8] = {{0.f}};
    for (int k0 = 0; k0 < K; k0 += KB) {
#pragma unroll
        for (int h = 0; h < 2; ++h) {
            int r = lr + h * 64;
            As[lc + 0][r] = va[h].x;
            As[lc + 1][r] = va[h].y;
            As[lc + 2][r] = va[h].z;
            As[lc + 3][r] = va[h].w;
            Bs[lc + 0][r] = vb[h].x;
            Bs[lc + 1][r] = vb[h].y;
            Bs[lc + 2][r] = vb[h].z;
            Bs[lc + 3][r] = vb[h].w;
        }
        __syncthreads();
        int k1 = k0 + KB;
        if (k1 < K) {
#pragma unroll
            for (int h = 0; h < 2; ++h) {
                int r = lr + h * 64;
                int gr = row0 + r;
                va[h] = (gr < M)
                            ? *(const float4*)&A[(size_t)gr * K + k1 + lc]
                            : make_float4(0.f, 0.f, 0.f, 0.f);
                vb[h] = *(const float4*)&B[(size_t)(col0 + r) * K + k1 + lc];
            }
        }
#pragma unroll
        for (int k = 0; k < KB; ++k) {
            float4 a0 = *(const float4*)&As[k][ty * 4];
            float4 a1 = *(const float4*)&As[k][64 + ty * 4];
            float4 b0 = *(const float4*)&Bs[k][tx * 4];
            float4 b1 = *(const float4*)&Bs[k][64 + tx * 4];
            float av[8] = {a0.x, a0.y, a0.z, a0.w, a1.x, a1.y, a1.z, a1.w};
            float bv[8] = {b0.x, b0.y, b0.z, b0.w, b1.x, b1.y, b1.z, b1.w};
#pragma unroll
            for (int i = 0; i < 8; ++i)
#pragma unroll
                for (int j = 0; j < 8; ++j) acc[i][j] += av[i] * bv[j];
        }
        __syncthreads();
    }
    const float bn_rs = rsqrtf(1.f + 1e-5f);
#pragma unroll
    for (int gj = 0; gj < 2; ++gj) {
        int nb = col0 + gj * 64 + tx * 4;
        float bs[4], sc[4], sh[4];
#pragma unroll
        for (int j = 0; j < 4; ++j) {
            bs[j] = bias[nb + j];
            if (mode == 0) {
                sc[j] = gamma[nb + j] * bn_rs;
                sh[j] = beta[nb + j];
            }
        }
#pragma unroll
        for (int gi = 0; gi < 2; ++gi) {
#pragma unroll
            for (int i2 = 0; i2 < 4; ++i2) {
                int m = row0 + gi * 64 + ty * 4 + i2;
                if (m >= M) continue;
                int i = gi * 4 + i2;
                float y[4];
#pragma unroll
                for (int j = 0; j < 4; ++j) {
                    float v = acc[i][gj * 4 + j] + bs[j];
                    if (mode == 0) v = v * sc[j] + sh[j];
                    if (mode == 0 || mode == 1) v = fmaxf(v, 0.f);
                    y[j] = v;
                }
                if (mode == 3) {
                    float2 o;
                    o.x = sig_tanh(y[0], y[1]);
                    o.y = sig_tanh(y[2], y[3]);
                    *(float2*)&C[(size_t)m * (NN / 2) + nb / 2] = o;
                } else if (mode == 4) {
                    __hip_bfloat162 o;
                    o.x = __float2bfloat16(sig_tanh(y[0], y[1]));
                    o.y = __float2bfloat16(sig_tanh(y[2], y[3]));
                    *(__hip_bfloat162*)((__hip_bfloat16*)C +
                                        (size_t)m * (NN / 2) + nb / 2) = o;
                } else {
                    float4 o = {y[0], y[1], y[2], y[3]};
                    *(float4*)&C[(size_t)m * NN + nb] = o;
                }
            }
        }
    }
}

// ---------------------------------------------------------------------------
// Instance norm over sorted batch segments (block = graph, thread = channel)
// ---------------------------------------------------------------------------
__device__ __forceinline__ int lowerb(const int* a, int n, int key) {
    int lo = 0, hi = n;
    while (lo < hi) {
        int mid = (lo + hi) >> 1;
        if (a[mid] < key) lo = mid + 1;
        else hi = mid;
    }
    return lo;
}

__global__ __launch_bounds__(256) void inst_norm_k(
    const float* __restrict__ x, const int* __restrict__ batch,
    float* __restrict__ y) {
    __shared__ int sS, sE;
    int g = blockIdx.x, t = threadIdx.x;
    if (t == 0) {
        sS = lowerb(batch, N_NODES, g);
        sE = lowerb(batch, N_NODES, g + 1);
    }
    __syncthreads();
    int s = sS, e = sE;
    float sum = 0.f, ss = 0.f;
    for (int n = s; n < e; ++n) {
        float v = x[(size_t)n * HH + t];
        sum += v;
        ss += v * v;
    }
    float c = (float)((e - s) > 0 ? (e - s) : 1);
    float mean = sum / c;
    float var = ss / c - mean * mean;
    float inv = rsqrtf(var + 1e-5f);
    for (int n = s; n < e; ++n) {
        float v = x[(size_t)n * HH + t];
        y[(size_t)n * HH + t] = (v - mean) * inv;
    }
}

// ---------------------------------------------------------------------------
// Fused: instance-norm + segment-max pool + linear + sigmoid (block = graph)
// ---------------------------------------------------------------------------
__global__ __launch_bounds__(256) void inpool_k(
    const float* __restrict__ x, const int* __restrict__ batch,
    const float* __restrict__ lw, const float* __restrict__ lb,
    float* __restrict__ out) {
    __shared__ float pooled[HH];
    __shared__ int sS, sE;
    int g = blockIdx.x, t = threadIdx.x;
    if (t == 0) {
        sS = lowerb(batch, N_NODES, g);
        sE = lowerb(batch, N_NODES, g + 1);
    }
    __syncthreads();
    int s = sS, e = sE;
    float sum = 0.f, ss = 0.f;
    for (int n = s; n < e; ++n) {
        float v = x[(size_t)n * HH + t];
        sum += v;
        ss += v * v;
    }
    float c = (float)((e - s) > 0 ? (e - s) : 1);
    float mean = sum / c;
    float var = ss / c - mean * mean;
    float inv = rsqrtf(var + 1e-5f);
    float m = -3.0e38f;
    for (int n = s; n < e; ++n) {
        float v = (x[(size_t)n * HH + t] - mean) * inv;
        m = fmaxf(m, v);
    }
    pooled[t] = (e > s) ? m : 0.f;
    __syncthreads();
    if (t < 10) {
        float acc = lb[t];
        for (int k = 0; k < HH; ++k) acc += pooled[k] * lw[t * HH + k];
        out[g * 10 + t] = fast_sigmoid(acc);
    }
}

// ---------------------------------------------------------------------------
extern "C" void kernel_launch(void* const* d_in, const int* in_sizes, int n_in,
                              void* d_out, int out_size, void* d_ws,
                              size_t ws_size, hipStream_t stream) {
    const float* x      = (const float*)d_in[0];
    const int*   ei     = (const int*)d_in[1];
    const float* eattr  = (const float*)d_in[2];
    const int*   batch  = (const int*)d_in[3];
    const float* nodeW  = (const float*)d_in[4];
    const float* nodeb  = (const float*)d_in[5];
    const float* edgeW  = (const float*)d_in[6];
    const float* edgeb  = (const float*)d_in[7];
    const float* t1     = (const float*)d_in[8];
    const float* g1w1   = (const float*)d_in[9];
    const float* g1b1   = (const float*)d_in[10];
    const float* g1g    = (const float*)d_in[11];
    const float* g1be   = (const float*)d_in[12];
    const float* g1w2   = (const float*)d_in[13];
    const float* g1b2   = (const float*)d_in[14];
    const float* t2     = (const float*)d_in[15];
    const float* g2w1   = (const float*)d_in[16];
    const float* g2b1   = (const float*)d_in[17];
    const float* g2g    = (const float*)d_in[18];
    const float* g2be   = (const float*)d_in[19];
    const float* g2w2   = (const float*)d_in[20];
    const float* g2b2   = (const float*)d_in[21];
    const float* linw   = (const float*)d_in[22];
    const float* linb   = (const float*)d_in[23];
    float* out = (float*)d_out;

    const int* srcA = ei;
    const int* dstA = ei + N_EDGES;

    float* F0  = (float*)d_ws;                   // [N,256]
    float* F1  = F0 + (size_t)N_NODES * HH;      // [N,256]
    float* F2  = F1 + (size_t)N_NODES * HH;      // [N,512]
    float* W2n = F2 + (size_t)N_NODES * 2 * HH;  // 512*64 interleaved
    float* b2n = W2n + 512 * 64;                 // 512
    float* W2e = b2n + 512;                      // 512*16 interleaved
    float* b2e = W2e + 512 * 16;                 // 512
    float* eattrs = b2e + 512;                   // E*16, CSR-ordered
    __hip_bfloat16* eacsr =
        (__hip_bfloat16*)(eattrs + (size_t)N_EDGES * FE);  // [E,256] bf16
    int* cnt    = (int*)(eacsr + (size_t)N_EDGES * HH);
    int* cursor = cnt + N_NODES;
    int* rowst  = cursor + N_NODES;              // N+1
    int* srcs   = rowst + N_NODES + 1;           // E, CSR-ordered
    int* bsum   = srcs + N_EDGES;                // 128

    const int NSCB = (N_NODES + 255) / 256;      // 79

    // --- CSR build ---
    hipMemsetAsync(cnt, 0, N_NODES * sizeof(int), stream);
    hist_k<<<(N_EDGES + 255) / 256, 256, 0, stream>>>(dstA, cnt);
    scan1_k<<<NSCB, 256, 0, stream>>>(cnt, rowst, bsum);
    scan2_k<<<1, 128, 0, stream>>>(bsum, NSCB);
    scan3_k<<<NSCB, 256, 0, stream>>>(cnt, bsum, rowst, cursor);
    scatter_k<<<(N_EDGES + 255) / 256, 256, 0, stream>>>(srcA, dstA, eattr,
                                                         cursor, srcs, eattrs);

    // --- weight repacks (interleaved i/g) ---
    repack_k<<<(512 * 64 + 512 + 255) / 256, 256, 0, stream>>>(nodeW, nodeb,
                                                               W2n, b2n, 64);
    repack_k<<<(512 * 16 + 512 + 255) / 256, 256, 0, stream>>>(edgeW, edgeb,
                                                               W2e, b2e, 16);

    dim3 gemm_grid1((N_NODES + TM - 1) / TM, 512 / TN);
    dim3 gemm_grid2((N_NODES + TM - 1) / TM, 256 / TN);

    // --- node LSTM via GEMM (fused activation, fp32 out) ---
    gemm_nt_k<<<gemm_grid1, 256, 0, stream>>>(x, W2n, b2n, nullptr, nullptr,
                                              F0, N_NODES, 512, 64, 3);
    // --- edge LSTM via GEMM over CSR-ordered attrs (fused act, bf16 out) ---
    gemm_nt_k<<<dim3(N_EDGES / TM, 512 / TN), 256, 0, stream>>>(
        eattrs, W2e, b2e, nullptr, nullptr, (float*)eacsr, N_EDGES, 512, 16, 4);

    // --- GENConv 1 ---
    genconv_edge_k<<<(N_NODES + NPB - 1) / NPB, 256, 0, stream>>>(
        F0, eacsr, srcs, rowst, t1, F1);
    gemm_nt_k<<<gemm_grid1, 256, 0, stream>>>(F1, g1w1, g1b1, g1g, g1be, F2,
                                              N_NODES, 512, 256, 0);
    gemm_nt_k<<<gemm_grid2, 256, 0, stream>>>(F2, g1w2, g1b2, nullptr, nullptr,
                                              F1, N_NODES, 256, 512, 1);
    inst_norm_k<<<GG, 256, 0, stream>>>(F1, batch, F0);

    // --- GENConv 2 ---
    genconv_edge_k<<<(N_NODES + NPB - 1) / NPB, 256, 0, stream>>>(
        F0, eacsr, srcs, rowst, t2, F1);
    gemm_nt_k<<<gemm_grid1, 256, 0, stream>>>(F1, g2w1, g2b1, g2g, g2be, F2,
                                              N_NODES, 512, 256, 0);
    gemm_nt_k<<<gemm_grid2, 256, 0, stream>>>(F2, g2w2, g2b2, nullptr, nullptr,
                                              F1, N_NODES, 256, 512, 1);

    // --- fused inst-norm + pool + linear + sigmoid ---
    inpool_k<<<GG, 256, 0, stream>>>(F1, batch, linw, linb, out);
}